// Round 8
// baseline (17734.296 us; speedup 1.0000x reference)
//
#include <hip/hip_runtime.h>
#include <hip/hip_bf16.h>
#include <hip/hip_cooperative_groups.h>

namespace cg = cooperative_groups;

#define HD 1024
#define BB 512
#define SS 64
#define N3 3072
#define NC 9216      // 3 * N3  (gi2 | gh1 | gh2)
#define ND 9
#define VC 4
#define KI 832       // padded K for init GEMM (784 -> 13*64)

typedef __attribute__((ext_vector_type(8))) short bf16x8;
typedef __attribute__((ext_vector_type(4))) float f32x4;

__device__ __forceinline__ ushort f2b(float f) {
    unsigned u = __builtin_bit_cast(unsigned, f);
    u += 0x7fffu + ((u >> 16) & 1u);          // round-to-nearest-even
    return (ushort)(u >> 16);
}

__device__ __forceinline__ float sigf(float x) {
    return 1.f / (1.f + __expf(-x));
}

__device__ __forceinline__ void gld_lds16(const void* g, void* l) {
    __builtin_amdgcn_global_load_lds(
        (const __attribute__((address_space(1))) unsigned int*)g,
        (__attribute__((address_space(3))) unsigned int*)l, 16, 0, 0);
}

struct PArgs {
    float* h1; float* h2; float* Cbuf; float* Wt1;
    ushort* h1b; ushort* h2b; ushort* Wcat; unsigned* ctr;
    const ushort* Acat; const ushort* W_inb;
    const float* note; const float* velc;
    const float* b_in; const float* b_ih1; const float* b_hh1;
    const float* b_ih2; const float* b_hh2;
    const float* W_out; const float* b_out;
    float* out;
};

// ============================================================================
// 64x64-tile MFMA GEMM core (R2-verified indexing), 32KB double-buffered LDS.
// ============================================================================
__device__ __forceinline__ void gemm64(
    const ushort* __restrict__ Ag, const ushort* __restrict__ Bg,
    int ks, int kiters, ushort* As, ushort* Bs, f32x4 acc[2][2])
{
    const int tid = threadIdx.x;
    const int w = tid >> 6, l = tid & 63;
    const int lr = l >> 3;
    const int sw = ((l & 7) ^ lr) << 3;        // XOR-swizzled 16B chunk

    const ushort* Ag0 = Ag + (size_t)(16 * w + lr) * ks + sw;
    const ushort* Ag1 = Ag0 + 8 * ks;
    const ushort* Bg0 = Bg + (size_t)(16 * w + lr) * ks + sw;
    const ushort* Bg1 = Bg0 + 8 * ks;
    const int o0 = (16 * w) * 64, o1 = (16 * w + 8) * 64;

    gld_lds16(Ag0, As + o0); gld_lds16(Ag1, As + o1);
    gld_lds16(Bg0, Bs + o0); gld_lds16(Bg1, Bs + o1);

    const int wm = (w >> 1) << 5, wn = (w & 1) << 5;
    const int fr = l & 15, fc = l >> 4;
    const int ra0 = wm + fr, ra1 = wm + 16 + fr;
    const int rb0 = wn + fr, rb1 = wn + 16 + fr;

    for (int kt = 0; kt < kiters; ++kt) {
        const int cb = (kt & 1) << 12;
        __syncthreads();                       // drains cur loads + prev reads
        if (kt + 1 < kiters) {
            const int nb = ((kt + 1) & 1) << 12;
            const int ko = (kt + 1) << 6;
            gld_lds16(Ag0 + ko, As + nb + o0);
            gld_lds16(Ag1 + ko, As + nb + o1);
            gld_lds16(Bg0 + ko, Bs + nb + o0);
            gld_lds16(Bg1 + ko, Bs + nb + o1);
        }
        #pragma unroll
        for (int kk = 0; kk < 2; ++kk) {
            const int c = (kk << 2) + fc;
            bf16x8 a0 = *(const bf16x8*)(As + cb + ra0 * 64 + ((c ^ (ra0 & 7)) << 3));
            bf16x8 a1 = *(const bf16x8*)(As + cb + ra1 * 64 + ((c ^ (ra1 & 7)) << 3));
            bf16x8 b0 = *(const bf16x8*)(Bs + cb + rb0 * 64 + ((c ^ (rb0 & 7)) << 3));
            bf16x8 b1 = *(const bf16x8*)(Bs + cb + rb1 * 64 + ((c ^ (rb1 & 7)) << 3));
            acc[0][0] = __builtin_amdgcn_mfma_f32_16x16x32_bf16(a0, b0, acc[0][0], 0, 0, 0);
            acc[0][1] = __builtin_amdgcn_mfma_f32_16x16x32_bf16(a0, b1, acc[0][1], 0, 0, 0);
            acc[1][0] = __builtin_amdgcn_mfma_f32_16x16x32_bf16(a1, b0, acc[1][0], 0, 0, 0);
            acc[1][1] = __builtin_amdgcn_mfma_f32_16x16x32_bf16(a1, b1, acc[1][1], 0, 0, 0);
        }
    }
    __syncthreads();   // protect LDS reuse across tiles/phases
}

__device__ __forceinline__ void cwrite(const f32x4 acc[2][2], int mt, int nt,
                                       float* __restrict__ Cbuf)
{
    const int tid = threadIdx.x;
    const int w = tid >> 6, l = tid & 63;
    const int wm = (w >> 1) << 5, wn = (w & 1) << 5;
    const int fr = l & 15, fc = l >> 4;
    float* Cw = Cbuf + (size_t)((mt << 6) + wm) * NC + (nt << 6) + wn;
    #pragma unroll
    for (int r = 0; r < 4; ++r) {
        const size_t ro0 = (size_t)(fc * 4 + r) * NC;
        const size_t ro1 = (size_t)(16 + fc * 4 + r) * NC;
        Cw[ro0 + fr]      = acc[0][0][r];
        Cw[ro0 + 16 + fr] = acc[0][1][r];
        Cw[ro1 + fr]      = acc[1][0][r];
        Cw[ro1 + 16 + fr] = acc[1][1][r];
    }
}

__device__ __forceinline__ void init_tile(const PArgs& a, int t, ushort* As, ushort* Bs)
{
    const int nt = t >> 3, mt = t & 7;
    f32x4 acc[2][2] = {};
    gemm64(a.Acat + ((size_t)(mt << 6)) * KI,
           a.W_inb + ((size_t)(nt << 6)) * KI, KI, 13, As, Bs, acc);
    const int tid = threadIdx.x;
    const int w = tid >> 6, l = tid & 63;
    const int wm = (w >> 1) << 5, wn = (w & 1) << 5;
    const int fr = l & 15, fc = l >> 4;
    const int row0 = (mt << 6) + wm;
    const int col0 = (nt << 6) + wn + fr;
    const float b0v = a.b_in[col0], b1v = a.b_in[col0 + 16];
    #pragma unroll
    for (int i = 0; i < 2; ++i) {
        #pragma unroll
        for (int r = 0; r < 4; ++r) {
            const int row = row0 + i * 16 + fc * 4 + r;
            const float v0 = tanhf(acc[i][0][r] + b0v);
            const float v1 = tanhf(acc[i][1][r] + b1v);
            a.h1[(size_t)row * HD + col0]       = v0;
            a.h1b[(size_t)row * HD + col0]      = f2b(v0);
            a.h1[(size_t)row * HD + col0 + 16]  = v1;
            a.h1b[(size_t)row * HD + col0 + 16] = f2b(v1);
        }
    }
}

__device__ __forceinline__ void main_tile(const PArgs& a, int nt, int mt,
                                          ushort* As, ushort* Bs)
{
    const ushort* Am = (nt < 96) ? a.h1b : a.h2b;
    f32x4 acc[2][2] = {};
    gemm64(Am + ((size_t)(mt << 6)) * HD,
           a.Wcat + ((size_t)(nt << 6)) * HD, HD, 16, As, Bs, acc);
    cwrite(acc, mt, nt, a.Cbuf);
}

// ============================================================================
// gru1_first: step-0 GRU1 (out_prev = 0) for row b; h2 <- h1. 256 thr x 4.
// ============================================================================
__device__ void gru1_first_pw(const PArgs& a, int b, float* sinp)
{
    const int tid = threadIdx.x;
    if (tid < 22) {
        float v = 0.f;
        if (tid >= 9 && tid < 18) v = a.note[(size_t)b * (SS * ND) + (tid - 9)];
        else if (tid >= 18)       v = a.velc[(size_t)b * (SS * VC) + (tid - 18)];
        sinp[tid] = v;
    }
    __syncthreads();
    #pragma unroll
    for (int k = 0; k < 4; ++k) {
        const int j = tid + (k << 8);
        float xir = a.b_ih1[j], xiz = a.b_ih1[HD + j], xin = a.b_ih1[2 * HD + j];
        #pragma unroll
        for (int c = 0; c < 22; ++c) {
            const float x = sinp[c];
            const float* wr = a.Wt1 + c * N3;
            xir = fmaf(x, wr[j], xir);
            xiz = fmaf(x, wr[HD + j], xiz);
            xin = fmaf(x, wr[2 * HD + j], xin);
        }
        const float* g1 = a.Cbuf + (size_t)b * NC + N3;
        const float hr = g1[j] + a.b_hh1[j];
        const float hz = g1[HD + j] + a.b_hh1[HD + j];
        const float hn = g1[2 * HD + j] + a.b_hh1[2 * HD + j];
        const float rg = sigf(xir + hr), zg = sigf(xiz + hz);
        const float n = tanhf(xin + rg * hn);
        const float hv = (1.f - zg) * n + zg * a.h1[(size_t)b * HD + j];
        const ushort hb = f2b(hv);
        a.h1[(size_t)b * HD + j] = hv;  a.h1b[(size_t)b * HD + j] = hb;
        a.h2[(size_t)b * HD + j] = hv;  a.h2b[(size_t)b * HD + j] = hb;
    }
    __syncthreads();
}

// ============================================================================
// pw_row: GRU2(s) -> h2 ; out(s) ; GRU1(s+1) -> h1.  Row b, 256 thr x 4.
// sred: LDS scratch >= 88 floats.
// ============================================================================
__device__ void pw_row(const PArgs& a, int b, int s, bool doGru1, float* sred)
{
    const int tid = threadIdx.x;
    float h2new[4];
    #pragma unroll
    for (int k = 0; k < 4; ++k) {
        const int j = tid + (k << 8);
        const float* gi = a.Cbuf + (size_t)b * NC;
        const float* gh = gi + 2 * N3;
        const float ir  = gi[j] + a.b_ih2[j];
        const float hr  = gh[j] + a.b_hh2[j];
        const float iz  = gi[HD + j] + a.b_ih2[HD + j];
        const float hz  = gh[HD + j] + a.b_hh2[HD + j];
        const float in_ = gi[2 * HD + j] + a.b_ih2[2 * HD + j];
        const float hn  = gh[2 * HD + j] + a.b_hh2[2 * HD + j];
        const float rg = sigf(ir + hr), zg = sigf(iz + hz);
        const float n = tanhf(in_ + rg * hn);
        const float hv = (1.f - zg) * n + zg * a.h2[(size_t)b * HD + j];
        a.h2[(size_t)b * HD + j]  = hv;
        a.h2b[(size_t)b * HD + j] = f2b(hv);
        h2new[k] = hv;
    }
    const int w = tid >> 6, l = tid & 63;
    #pragma unroll
    for (int d = 0; d < ND; ++d) {
        float p = 0.f;
        #pragma unroll
        for (int k = 0; k < 4; ++k)
            p = fmaf(h2new[k], a.W_out[d * HD + tid + (k << 8)], p);
        #pragma unroll
        for (int off = 32; off > 0; off >>= 1) p += __shfl_down(p, off);
        if (l == 0) sred[w * 16 + d] = p;
    }
    __syncthreads();
    float* sinp = sred + 64;
    if (tid < ND) {
        float acc2 = a.b_out[tid];
        #pragma unroll
        for (int w2 = 0; w2 < 4; ++w2) acc2 += sred[w2 * 16 + tid];
        const float o = sigf(acc2);
        a.out[(size_t)b * (SS * ND) + s * ND + tid] = o;
        sinp[tid] = o;
    } else if (tid >= ND && tid < 22 && doGru1) {
        sinp[tid] = (tid < 18)
            ? a.note[(size_t)b * (SS * ND) + (s + 1) * ND + (tid - 9)]
            : a.velc[(size_t)b * (SS * VC) + (s + 1) * VC + (tid - 18)];
    }
    __syncthreads();
    if (doGru1) {
        #pragma unroll
        for (int k = 0; k < 4; ++k) {
            const int j = tid + (k << 8);
            float xir = a.b_ih1[j], xiz = a.b_ih1[HD + j], xin = a.b_ih1[2 * HD + j];
            #pragma unroll
            for (int c = 0; c < 22; ++c) {
                const float x = sinp[c];
                const float* wr = a.Wt1 + c * N3;
                xir = fmaf(x, wr[j], xir);
                xiz = fmaf(x, wr[HD + j], xiz);
                xin = fmaf(x, wr[2 * HD + j], xin);
            }
            const float* g1 = a.Cbuf + (size_t)b * NC + N3;
            const float hr = g1[j] + a.b_hh1[j];
            const float hz = g1[HD + j] + a.b_hh1[HD + j];
            const float hn = g1[2 * HD + j] + a.b_hh1[2 * HD + j];
            const float rg = sigf(xir + hr), zg = sigf(xiz + hz);
            const float n = tanhf(xin + rg * hn);
            const float hv = (1.f - zg) * n + zg * a.h1[(size_t)b * HD + j];
            a.h1[(size_t)b * HD + j]  = hv;
            a.h1b[(size_t)b * HD + j] = f2b(hv);
        }
    }
    __syncthreads();
}

// ============================================================================
// Persistent cooperative kernel (grid = 256 or 512, adapts via gridDim.x).
// Tile stealing: ONE atomic per block (tid 0), LDS-broadcast to all threads.
// ============================================================================
__global__ void __launch_bounds__(256, 2) persist(PArgs a)
{
    cg::grid_group grid = cg::this_grid();
    __shared__ __align__(16) ushort As[2 * 4096];
    __shared__ __align__(16) ushort Bs[2 * 4096];
    __shared__ int s_lt;
    const int nb  = gridDim.x;
    const int bid = blockIdx.x;
    const int rpb = BB / nb;                    // rows per block: 1 or 2

    for (int i = bid; i < SS * 8; i += nb) a.ctr[i] = 0u;   // reset steal ctrs
    for (int t = bid; t < 128; t += nb) init_tile(a, t, As, Bs);
    grid.sync();

    for (int t = bid; t < 384; t += nb) {       // prologue gh1(0): nt 48..95
        main_tile(a, 48 + (t >> 3), t & 7, As, Bs);
    }
    grid.sync();

    for (int r = 0; r < rpb; ++r) gru1_first_pw(a, bid * rpb + r, (float*)As);
    grid.sync();

    const int x = bid & 7, rnk = bid >> 3, base = nb >> 3;
    for (int s = 0; s < SS; ++s) {
        unsigned* c = a.ctr + s * 8 + x;
        int lt = rnk;                            // group x owns n-tiles [18x,18x+18)
        while (lt < 144) {
            main_tile(a, x * 18 + (lt >> 3), lt & 7, As, Bs);
            // block-uniform steal: one atomic, broadcast via LDS
            if (threadIdx.x == 0) s_lt = base + (int)atomicAdd(c, 1u);
            __syncthreads();
            lt = s_lt;
            __syncthreads();
        }
        grid.sync();
        for (int r = 0; r < rpb; ++r)
            pw_row(a, bid * rpb + r, s, s + 1 < SS, (float*)As);
        grid.sync();
    }
}

// ============================================================================
// Fallback kernels (identical math via the same device functions)
// ============================================================================
__global__ __launch_bounds__(256) void k_init(PArgs a)
{
    __shared__ __align__(16) ushort As[2 * 4096];
    __shared__ __align__(16) ushort Bs[2 * 4096];
    init_tile(a, blockIdx.x, As, Bs);
}

__global__ __launch_bounds__(256) void k_gemm(PArgs a, int ntb)
{
    __shared__ __align__(16) ushort As[2 * 4096];
    __shared__ __align__(16) ushort Bs[2 * 4096];
    const int flat = blockIdx.x + (blockIdx.y << 3);
    const int id   = (flat & 7) * gridDim.y + (flat >> 3);  // XCD-contiguous
    main_tile(a, (id >> 3) + ntb, id & 7, As, Bs);
}

__global__ __launch_bounds__(256) void k_pwf(PArgs a)
{
    __shared__ float sred[96];
    gru1_first_pw(a, blockIdx.x, sred);
}

__global__ __launch_bounds__(256) void k_pw(PArgs a, int s)
{
    __shared__ float sred[96];
    pw_row(a, blockIdx.x, s, s + 1 < SS, sred);
}

// ============================================================================
// prep kernels
// ============================================================================
__global__ __launch_bounds__(256) void prep_w(
    const float* __restrict__ Wih2, const float* __restrict__ Whh1,
    const float* __restrict__ Whh2, ushort* __restrict__ Wcat)
{
    const int row = blockIdx.x;
    const float* src = row < 3072 ? Wih2 + (size_t)row * HD
                     : row < 6144 ? Whh1 + (size_t)(row - 3072) * HD
                                  : Whh2 + (size_t)(row - 6144) * HD;
    const int c = threadIdx.x * 4;
    float4 v = *(const float4*)(src + c);
    ushort4 o;
    o.x = f2b(v.x); o.y = f2b(v.y); o.z = f2b(v.z); o.w = f2b(v.w);
    *(ushort4*)(Wcat + (size_t)row * HD + c) = o;
}

__global__ __launch_bounds__(256) void prep_wt1(
    const float* __restrict__ Wih1, float* __restrict__ Wt1)
{
    const int g = blockIdx.x * 256 + threadIdx.x;
    #pragma unroll
    for (int c = 0; c < 22; ++c)
        Wt1[c * N3 + g] = Wih1[(size_t)g * 22 + c];
}

__global__ __launch_bounds__(256) void prep_acat(
    const float* __restrict__ z, const float* __restrict__ ne,
    const float* __restrict__ gc, ushort* __restrict__ Acat)
{
    const int b = blockIdx.x;
    const int t = threadIdx.x;
    if (t >= 208) return;
    const int c = t * 4;
    float4 v = make_float4(0.f, 0.f, 0.f, 0.f);
    if (c < 256)      v = *(const float4*)(z  + (size_t)b * 256 + c);
    else if (c < 768) v = *(const float4*)(ne + (size_t)b * 512 + (c - 256));
    else if (c < 784) v = *(const float4*)(gc + (size_t)b * 16  + (c - 768));
    ushort4 o;
    o.x = f2b(v.x); o.y = f2b(v.y); o.z = f2b(v.z); o.w = f2b(v.w);
    *(ushort4*)(Acat + (size_t)b * KI + c) = o;
}

__global__ __launch_bounds__(256) void prep_win(
    const float* __restrict__ W_in, ushort* __restrict__ W_inb)
{
    const int r = blockIdx.x;
    const int t = threadIdx.x;
    if (t >= 208) return;
    const int c = t * 4;
    ushort4 o = {0, 0, 0, 0};
    if (c < 784) {
        float4 v = *(const float4*)(W_in + (size_t)r * 784 + c);
        o.x = f2b(v.x); o.y = f2b(v.y); o.z = f2b(v.z); o.w = f2b(v.w);
    }
    *(ushort4*)(W_inb + (size_t)r * KI + c) = o;
}

// ============================================================================
extern "C" void kernel_launch(void* const* d_in, const int* in_sizes, int n_in,
                              void* d_out, int out_size, void* d_ws, size_t ws_size,
                              hipStream_t stream)
{
    const float* z     = (const float*)d_in[0];
    const float* ne    = (const float*)d_in[1];
    const float* note  = (const float*)d_in[3];
    const float* velc  = (const float*)d_in[4];
    const float* gc    = (const float*)d_in[5];
    const float* W_in  = (const float*)d_in[6];
    const float* b_in  = (const float*)d_in[7];
    const float* W_ih1 = (const float*)d_in[8];
    const float* W_hh1 = (const float*)d_in[9];
    const float* b_ih1 = (const float*)d_in[10];
    const float* b_hh1 = (const float*)d_in[11];
    const float* W_ih2 = (const float*)d_in[12];
    const float* W_hh2 = (const float*)d_in[13];
    const float* b_ih2 = (const float*)d_in[14];
    const float* b_hh2 = (const float*)d_in[15];
    const float* W_out = (const float*)d_in[16];
    const float* b_out = (const float*)d_in[17];
    float* out = (float*)d_out;

    // workspace layout (~44.3 MB)
    float*  h1   = (float*)d_ws;                     // [512*1024]
    float*  h2   = h1 + BB * HD;                     // [512*1024]
    float*  Cbuf = h2 + BB * HD;                     // [512*9216]
    float*  Wt1  = Cbuf + (size_t)BB * NC;           // [22*3072]
    unsigned* ctr = (unsigned*)(Wt1 + 22 * N3);      // [512]
    ushort* h1b  = (ushort*)(ctr + 512);             // [512*1024]
    ushort* h2b  = h1b + BB * HD;                    // [512*1024]
    ushort* Wcat = h2b + BB * HD;                    // [9216*1024]
    // init-only buffers aliased into Cbuf (consumed before Cbuf is written)
    ushort* Acat  = (ushort*)Cbuf;                   // [512*832]
    ushort* W_inb = Acat + (size_t)BB * KI;          // [1024*832]

    prep_w   <<<dim3(NC), 256, 0, stream>>>(W_ih2, W_hh1, W_hh2, Wcat);
    prep_wt1 <<<dim3(12), 256, 0, stream>>>(W_ih1, Wt1);
    prep_acat<<<dim3(BB), 256, 0, stream>>>(z, ne, gc, Acat);
    prep_win <<<dim3(HD), 256, 0, stream>>>(W_in, W_inb);

    PArgs pa;
    pa.h1 = h1; pa.h2 = h2; pa.Cbuf = Cbuf; pa.Wt1 = Wt1;
    pa.h1b = h1b; pa.h2b = h2b; pa.Wcat = Wcat; pa.ctr = ctr;
    pa.Acat = Acat; pa.W_inb = W_inb;
    pa.note = note; pa.velc = velc;
    pa.b_in = b_in; pa.b_ih1 = b_ih1; pa.b_hh1 = b_hh1;
    pa.b_ih2 = b_ih2; pa.b_hh2 = b_hh2;
    pa.W_out = W_out; pa.b_out = b_out;
    pa.out = out;

    // Try the persistent cooperative kernel; fall back to multi-launch if
    // the runtime rejects it (identical math either way -> same output).
    int occ = 0;
    hipError_t qe = hipOccupancyMaxActiveBlocksPerMultiprocessor(
        &occ, (const void*)persist, 256, 0);
    hipError_t le = hipErrorUnknown;
    if (qe == hipSuccess && occ >= 1) {
        const int nblk = (occ >= 2) ? 512 : 256;
        void* args[] = { &pa };
        le = hipLaunchCooperativeKernel((const void*)persist, dim3(nblk),
                                        dim3(256), args, 0, stream);
    }
    if (le != hipSuccess) {
        k_init<<<dim3(128), 256, 0, stream>>>(pa);
        k_gemm<<<dim3(8, 48), 256, 0, stream>>>(pa, 48);   // prologue gh1(0)
        k_pwf <<<dim3(BB), 256, 0, stream>>>(pa);
        for (int s = 0; s < SS; ++s) {
            k_gemm<<<dim3(8, 144), 256, 0, stream>>>(pa, 0);
            k_pw  <<<dim3(BB), 256, 0, stream>>>(pa, s);
        }
    }
}

// Round 9
// 2894.088 us; speedup vs baseline: 6.1278x; 6.1278x over previous
//
#include <hip/hip_runtime.h>
#include <hip/hip_bf16.h>

#define HD 1024
#define BB 512
#define SS 64
#define N3 3072
#define NC 9216      // 3 * N3  (gi2 | gh1 | gh2)
#define ND 9
#define VC 4
#define KI 832       // padded K for init GEMM (784 -> 13*64)

typedef __attribute__((ext_vector_type(8))) short bf16x8;
typedef __attribute__((ext_vector_type(4))) float f32x4;

__device__ __forceinline__ ushort f2b(float f) {
    unsigned u = __builtin_bit_cast(unsigned, f);
    u += 0x7fffu + ((u >> 16) & 1u);          // round-to-nearest-even
    return (ushort)(u >> 16);
}

__device__ __forceinline__ float sigf(float x) {
    return 1.f / (1.f + __expf(-x));
}

__device__ __forceinline__ void gld_lds16(const void* g, void* l) {
    __builtin_amdgcn_global_load_lds(
        (const __attribute__((address_space(1))) unsigned int*)g,
        (__attribute__((address_space(3))) unsigned int*)l, 16, 0, 0);
}

struct PArgs {
    float* h1; float* h2; float* Cbuf; float* Wt1;
    ushort* h1b; ushort* h2b; ushort* Wcat;
    const ushort* Acat; const ushort* W_inb;
    const float* note; const float* velc;
    const float* b_in; const float* b_ih1; const float* b_hh1;
    const float* b_ih2; const float* b_hh2;
    const float* W_out; const float* b_out;
    float* out;
};

// ============================================================================
// 64x64-tile MFMA GEMM core (R2-verified indexing), 32KB double-buffered LDS.
// ============================================================================
__device__ __forceinline__ void gemm64(
    const ushort* __restrict__ Ag, const ushort* __restrict__ Bg,
    int ks, int kiters, ushort* As, ushort* Bs, f32x4 acc[2][2])
{
    const int tid = threadIdx.x;
    const int w = tid >> 6, l = tid & 63;
    const int lr = l >> 3;
    const int sw = ((l & 7) ^ lr) << 3;        // XOR-swizzled 16B chunk

    const ushort* Ag0 = Ag + (size_t)(16 * w + lr) * ks + sw;
    const ushort* Ag1 = Ag0 + 8 * ks;
    const ushort* Bg0 = Bg + (size_t)(16 * w + lr) * ks + sw;
    const ushort* Bg1 = Bg0 + 8 * ks;
    const int o0 = (16 * w) * 64, o1 = (16 * w + 8) * 64;

    gld_lds16(Ag0, As + o0); gld_lds16(Ag1, As + o1);
    gld_lds16(Bg0, Bs + o0); gld_lds16(Bg1, Bs + o1);

    const int wm = (w >> 1) << 5, wn = (w & 1) << 5;
    const int fr = l & 15, fc = l >> 4;
    const int ra0 = wm + fr, ra1 = wm + 16 + fr;
    const int rb0 = wn + fr, rb1 = wn + 16 + fr;

    for (int kt = 0; kt < kiters; ++kt) {
        const int cb = (kt & 1) << 12;
        __syncthreads();                       // drains cur loads + prev reads
        if (kt + 1 < kiters) {
            const int nb = ((kt + 1) & 1) << 12;
            const int ko = (kt + 1) << 6;
            gld_lds16(Ag0 + ko, As + nb + o0);
            gld_lds16(Ag1 + ko, As + nb + o1);
            gld_lds16(Bg0 + ko, Bs + nb + o0);
            gld_lds16(Bg1 + ko, Bs + nb + o1);
        }
        #pragma unroll
        for (int kk = 0; kk < 2; ++kk) {
            const int c = (kk << 2) + fc;
            bf16x8 a0 = *(const bf16x8*)(As + cb + ra0 * 64 + ((c ^ (ra0 & 7)) << 3));
            bf16x8 a1 = *(const bf16x8*)(As + cb + ra1 * 64 + ((c ^ (ra1 & 7)) << 3));
            bf16x8 b0 = *(const bf16x8*)(Bs + cb + rb0 * 64 + ((c ^ (rb0 & 7)) << 3));
            bf16x8 b1 = *(const bf16x8*)(Bs + cb + rb1 * 64 + ((c ^ (rb1 & 7)) << 3));
            acc[0][0] = __builtin_amdgcn_mfma_f32_16x16x32_bf16(a0, b0, acc[0][0], 0, 0, 0);
            acc[0][1] = __builtin_amdgcn_mfma_f32_16x16x32_bf16(a0, b1, acc[0][1], 0, 0, 0);
            acc[1][0] = __builtin_amdgcn_mfma_f32_16x16x32_bf16(a1, b0, acc[1][0], 0, 0, 0);
            acc[1][1] = __builtin_amdgcn_mfma_f32_16x16x32_bf16(a1, b1, acc[1][1], 0, 0, 0);
        }
    }
}

__device__ __forceinline__ void cwrite(const f32x4 acc[2][2], int mt, int nt,
                                       float* __restrict__ Cbuf)
{
    const int tid = threadIdx.x;
    const int w = tid >> 6, l = tid & 63;
    const int wm = (w >> 1) << 5, wn = (w & 1) << 5;
    const int fr = l & 15, fc = l >> 4;
    float* Cw = Cbuf + (size_t)((mt << 6) + wm) * NC + (nt << 6) + wn;
    #pragma unroll
    for (int r = 0; r < 4; ++r) {
        const size_t ro0 = (size_t)(fc * 4 + r) * NC;
        const size_t ro1 = (size_t)(16 + fc * 4 + r) * NC;
        Cw[ro0 + fr]      = acc[0][0][r];
        Cw[ro0 + 16 + fr] = acc[0][1][r];
        Cw[ro1 + fr]      = acc[1][0][r];
        Cw[ro1 + 16 + fr] = acc[1][1][r];
    }
}

// ============================================================================
// k_init: h1 = tanh(Acat @ W_inb^T + b_in)  (128 tiles; K=832)
// ============================================================================
__global__ __launch_bounds__(256) void k_init(PArgs a)
{
    __shared__ __align__(16) ushort As[2 * 4096];
    __shared__ __align__(16) ushort Bs[2 * 4096];
    const int t = blockIdx.x;
    const int nt = t >> 3, mt = t & 7;
    f32x4 acc[2][2] = {};
    gemm64(a.Acat + ((size_t)(mt << 6)) * KI,
           a.W_inb + ((size_t)(nt << 6)) * KI, KI, 13, As, Bs, acc);
    const int tid = threadIdx.x;
    const int w = tid >> 6, l = tid & 63;
    const int wm = (w >> 1) << 5, wn = (w & 1) << 5;
    const int fr = l & 15, fc = l >> 4;
    const int row0 = (mt << 6) + wm;
    const int col0 = (nt << 6) + wn + fr;
    const float b0v = a.b_in[col0], b1v = a.b_in[col0 + 16];
    #pragma unroll
    for (int i = 0; i < 2; ++i) {
        #pragma unroll
        for (int r = 0; r < 4; ++r) {
            const int row = row0 + i * 16 + fc * 4 + r;
            const float v0 = tanhf(acc[i][0][r] + b0v);
            const float v1 = tanhf(acc[i][1][r] + b1v);
            a.h1[(size_t)row * HD + col0]       = v0;
            a.h1b[(size_t)row * HD + col0]      = f2b(v0);
            a.h1[(size_t)row * HD + col0 + 16]  = v1;
            a.h1b[(size_t)row * HD + col0 + 16] = f2b(v1);
        }
    }
}

// ============================================================================
// k_gemm: C[512, 64*ntiles] sections; one 64x64 tile per block.
// grid (8, NT), XCD-chunked bijective swizzle.
// ============================================================================
__global__ __launch_bounds__(256) void k_gemm(PArgs a, int ntb)
{
    __shared__ __align__(16) ushort As[2 * 4096];
    __shared__ __align__(16) ushort Bs[2 * 4096];
    const int flat = blockIdx.x + (blockIdx.y << 3);
    const int id   = (flat & 7) * gridDim.y + (flat >> 3);  // XCD-contiguous
    const int nt   = (id >> 3) + ntb;
    const int mt   = id & 7;
    const ushort* Am = (nt < 96) ? a.h1b : a.h2b;
    f32x4 acc[2][2] = {};
    gemm64(Am + ((size_t)(mt << 6)) * HD,
           a.Wcat + ((size_t)(nt << 6)) * HD, HD, 16, As, Bs, acc);
    cwrite(acc, mt, nt, a.Cbuf);
}

// ============================================================================
// k_pwf: step-0 GRU1 (out_prev = 0) for row b; h2 <- h1. 256 thr x 4 cols.
// ============================================================================
__global__ __launch_bounds__(256) void k_pwf(PArgs a)
{
    __shared__ float sinp[22];
    const int b = blockIdx.x;
    const int tid = threadIdx.x;
    if (tid < 22) {
        float v = 0.f;
        if (tid >= 9 && tid < 18) v = a.note[(size_t)b * (SS * ND) + (tid - 9)];
        else if (tid >= 18)       v = a.velc[(size_t)b * (SS * VC) + (tid - 18)];
        sinp[tid] = v;
    }
    __syncthreads();
    #pragma unroll
    for (int k = 0; k < 4; ++k) {
        const int j = tid + (k << 8);
        float xir = a.b_ih1[j], xiz = a.b_ih1[HD + j], xin = a.b_ih1[2 * HD + j];
        #pragma unroll
        for (int c = 0; c < 22; ++c) {
            const float x = sinp[c];
            const float* wr = a.Wt1 + c * N3;
            xir = fmaf(x, wr[j], xir);
            xiz = fmaf(x, wr[HD + j], xiz);
            xin = fmaf(x, wr[2 * HD + j], xin);
        }
        const float* g1 = a.Cbuf + (size_t)b * NC + N3;
        const float hr = g1[j] + a.b_hh1[j];
        const float hz = g1[HD + j] + a.b_hh1[HD + j];
        const float hn = g1[2 * HD + j] + a.b_hh1[2 * HD + j];
        const float rg = sigf(xir + hr), zg = sigf(xiz + hz);
        const float n = tanhf(xin + rg * hn);
        const float hv = (1.f - zg) * n + zg * a.h1[(size_t)b * HD + j];
        const ushort hb = f2b(hv);
        a.h1[(size_t)b * HD + j] = hv;  a.h1b[(size_t)b * HD + j] = hb;
        a.h2[(size_t)b * HD + j] = hv;  a.h2b[(size_t)b * HD + j] = hb;
    }
}

// ============================================================================
// k_pw: per block TWO batch rows, float4-vectorized.
// GRU2(s) -> h2 ; out(s) ; GRU1(s+1) -> h1.  grid (256) x 256 threads.
// Thread t owns cols 4t..4t+3 of both rows.
// ============================================================================
__global__ __launch_bounds__(256) void k_pw(PArgs a, int s)
{
    __shared__ float sred[2][64];
    __shared__ float sinp[2][24];
    const int t  = threadIdx.x;
    const int b0 = blockIdx.x * 2;
    const bool doG1 = (s + 1 < SS);
    const int j4 = t << 2;

    // stage next-step note/velc for both rows (cols 9..21 of sinp)
    if (doG1 && t < 64) {
        const int r = t >> 5, c = t & 31;
        const int b = b0 + r;
        if (c >= 9 && c < 22)
            sinp[r][c] = (c < 18)
                ? a.note[(size_t)b * (SS * ND) + (s + 1) * ND + (c - 9)]
                : a.velc[(size_t)b * (SS * VC) + (s + 1) * VC + (c - 18)];
    }

    float4 bir = *(const float4*)(a.b_ih2 + j4);
    float4 biz = *(const float4*)(a.b_ih2 + HD + j4);
    float4 bin = *(const float4*)(a.b_ih2 + 2 * HD + j4);
    float4 bhr = *(const float4*)(a.b_hh2 + j4);
    float4 bhz = *(const float4*)(a.b_hh2 + HD + j4);
    float4 bhn = *(const float4*)(a.b_hh2 + 2 * HD + j4);
    const float *qir = (const float*)&bir, *qiz = (const float*)&biz,
                *qin = (const float*)&bin, *qhr = (const float*)&bhr,
                *qhz = (const float*)&bhz, *qhn = (const float*)&bhn;

    float h2n[2][4];
    #pragma unroll
    for (int r = 0; r < 2; ++r) {
        const int b = b0 + r;
        const float* gi = a.Cbuf + (size_t)b * NC;
        const float* gh = gi + 2 * N3;
        float4 vir = *(const float4*)(gi + j4);
        float4 viz = *(const float4*)(gi + HD + j4);
        float4 vin = *(const float4*)(gi + 2 * HD + j4);
        float4 vhr = *(const float4*)(gh + j4);
        float4 vhz = *(const float4*)(gh + HD + j4);
        float4 vhn = *(const float4*)(gh + 2 * HD + j4);
        float4 vh2 = *(const float4*)(a.h2 + (size_t)b * HD + j4);
        const float *pir = (const float*)&vir, *piz = (const float*)&viz,
                    *pin = (const float*)&vin, *phr = (const float*)&vhr,
                    *phz = (const float*)&vhz, *phn = (const float*)&vhn,
                    *ph2 = (const float*)&vh2;
        float hv[4];
        #pragma unroll
        for (int k = 0; k < 4; ++k) {
            const float rg = sigf(pir[k] + qir[k] + phr[k] + qhr[k]);
            const float zg = sigf(piz[k] + qiz[k] + phz[k] + qhz[k]);
            const float n  = tanhf(pin[k] + qin[k] + rg * (phn[k] + qhn[k]));
            hv[k] = (1.f - zg) * n + zg * ph2[k];
            h2n[r][k] = hv[k];
        }
        *(float4*)(a.h2 + (size_t)b * HD + j4) = *(float4*)hv;
        ushort4 hb;
        hb.x = f2b(hv[0]); hb.y = f2b(hv[1]); hb.z = f2b(hv[2]); hb.w = f2b(hv[3]);
        *(ushort4*)(a.h2b + (size_t)b * HD + j4) = hb;
    }

    // out projection: 9 dots x 2 rows (W_out float4 shared across rows)
    const int w = t >> 6, l = t & 63;
    #pragma unroll
    for (int d = 0; d < ND; ++d) {
        float4 wv = *(const float4*)(a.W_out + (size_t)d * HD + j4);
        const float* pwv = (const float*)&wv;
        float p0 = 0.f, p1 = 0.f;
        #pragma unroll
        for (int k = 0; k < 4; ++k) {
            p0 = fmaf(h2n[0][k], pwv[k], p0);
            p1 = fmaf(h2n[1][k], pwv[k], p1);
        }
        #pragma unroll
        for (int off = 32; off > 0; off >>= 1) {
            p0 += __shfl_down(p0, off);
            p1 += __shfl_down(p1, off);
        }
        if (l == 0) { sred[0][w * 16 + d] = p0; sred[1][w * 16 + d] = p1; }
    }
    __syncthreads();
    if (t < ND) {
        float acc2 = a.b_out[t];
        #pragma unroll
        for (int w2 = 0; w2 < 4; ++w2) acc2 += sred[0][w2 * 16 + t];
        const float o = sigf(acc2);
        a.out[(size_t)b0 * (SS * ND) + s * ND + t] = o;
        sinp[0][t] = o;
    } else if (t >= 64 && t < 64 + ND) {
        const int d = t - 64;
        float acc2 = a.b_out[d];
        #pragma unroll
        for (int w2 = 0; w2 < 4; ++w2) acc2 += sred[1][w2 * 16 + d];
        const float o = sigf(acc2);
        a.out[(size_t)(b0 + 1) * (SS * ND) + s * ND + d] = o;
        sinp[1][d] = o;
    }
    __syncthreads();

    // GRU1 for step s+1, both rows; Wt1 float4 loads shared across rows
    if (doG1) {
        float4 c1r = *(const float4*)(a.b_ih1 + j4);
        float4 c1z = *(const float4*)(a.b_ih1 + HD + j4);
        float4 c1n = *(const float4*)(a.b_ih1 + 2 * HD + j4);
        float xr[2][4], xz[2][4], xn[2][4];
        #pragma unroll
        for (int r = 0; r < 2; ++r) {
            *(float4*)xr[r] = c1r; *(float4*)xz[r] = c1z; *(float4*)xn[r] = c1n;
        }
        #pragma unroll
        for (int c = 0; c < 22; ++c) {
            float4 w0 = *(const float4*)(a.Wt1 + c * N3 + j4);
            float4 w1 = *(const float4*)(a.Wt1 + c * N3 + HD + j4);
            float4 w2v = *(const float4*)(a.Wt1 + c * N3 + 2 * HD + j4);
            const float *p0 = (const float*)&w0, *p1 = (const float*)&w1,
                        *p2 = (const float*)&w2v;
            #pragma unroll
            for (int r = 0; r < 2; ++r) {
                const float x = sinp[r][c];
                #pragma unroll
                for (int k = 0; k < 4; ++k) {
                    xr[r][k] = fmaf(x, p0[k], xr[r][k]);
                    xz[r][k] = fmaf(x, p1[k], xz[r][k]);
                    xn[r][k] = fmaf(x, p2[k], xn[r][k]);
                }
            }
        }
        float4 d1r = *(const float4*)(a.b_hh1 + j4);
        float4 d1z = *(const float4*)(a.b_hh1 + HD + j4);
        float4 d1n = *(const float4*)(a.b_hh1 + 2 * HD + j4);
        const float *e1r = (const float*)&d1r, *e1z = (const float*)&d1z,
                    *e1n = (const float*)&d1n;
        #pragma unroll
        for (int r = 0; r < 2; ++r) {
            const int b = b0 + r;
            const float* g1 = a.Cbuf + (size_t)b * NC + N3;
            float4 vhr = *(const float4*)(g1 + j4);
            float4 vhz = *(const float4*)(g1 + HD + j4);
            float4 vhn = *(const float4*)(g1 + 2 * HD + j4);
            float4 vh1 = *(const float4*)(a.h1 + (size_t)b * HD + j4);
            const float *phr = (const float*)&vhr, *phz = (const float*)&vhz,
                        *phn = (const float*)&vhn, *ph1 = (const float*)&vh1;
            float hv[4];
            #pragma unroll
            for (int k = 0; k < 4; ++k) {
                const float rg = sigf(xr[r][k] + phr[k] + e1r[k]);
                const float zg = sigf(xz[r][k] + phz[k] + e1z[k]);
                const float n  = tanhf(xn[r][k] + rg * (phn[k] + e1n[k]));
                hv[k] = (1.f - zg) * n + zg * ph1[k];
            }
            *(float4*)(a.h1 + (size_t)b * HD + j4) = *(float4*)hv;
            ushort4 hb;
            hb.x = f2b(hv[0]); hb.y = f2b(hv[1]); hb.z = f2b(hv[2]); hb.w = f2b(hv[3]);
            *(ushort4*)(a.h1b + (size_t)b * HD + j4) = hb;
        }
    }
}

// ============================================================================
// prep kernels
// ============================================================================
__global__ __launch_bounds__(256) void prep_w(
    const float* __restrict__ Wih2, const float* __restrict__ Whh1,
    const float* __restrict__ Whh2, ushort* __restrict__ Wcat)
{
    const int row = blockIdx.x;
    const float* src = row < 3072 ? Wih2 + (size_t)row * HD
                     : row < 6144 ? Whh1 + (size_t)(row - 3072) * HD
                                  : Whh2 + (size_t)(row - 6144) * HD;
    const int c = threadIdx.x * 4;
    float4 v = *(const float4*)(src + c);
    ushort4 o;
    o.x = f2b(v.x); o.y = f2b(v.y); o.z = f2b(v.z); o.w = f2b(v.w);
    *(ushort4*)(Wcat + (size_t)row * HD + c) = o;
}

__global__ __launch_bounds__(256) void prep_wt1(
    const float* __restrict__ Wih1, float* __restrict__ Wt1)
{
    const int g = blockIdx.x * 256 + threadIdx.x;
    #pragma unroll
    for (int c = 0; c < 22; ++c)
        Wt1[c * N3 + g] = Wih1[(size_t)g * 22 + c];
}

__global__ __launch_bounds__(256) void prep_acat(
    const float* __restrict__ z, const float* __restrict__ ne,
    const float* __restrict__ gc, ushort* __restrict__ Acat)
{
    const int b = blockIdx.x;
    const int t = threadIdx.x;
    if (t >= 208) return;
    const int c = t * 4;
    float4 v = make_float4(0.f, 0.f, 0.f, 0.f);
    if (c < 256)      v = *(const float4*)(z  + (size_t)b * 256 + c);
    else if (c < 768) v = *(const float4*)(ne + (size_t)b * 512 + (c - 256));
    else if (c < 784) v = *(const float4*)(gc + (size_t)b * 16  + (c - 768));
    ushort4 o;
    o.x = f2b(v.x); o.y = f2b(v.y); o.z = f2b(v.z); o.w = f2b(v.w);
    *(ushort4*)(Acat + (size_t)b * KI + c) = o;
}

__global__ __launch_bounds__(256) void prep_win(
    const float* __restrict__ W_in, ushort* __restrict__ W_inb)
{
    const int r = blockIdx.x;
    const int t = threadIdx.x;
    if (t >= 208) return;
    const int c = t * 4;
    ushort4 o = {0, 0, 0, 0};
    if (c < 784) {
        float4 v = *(const float4*)(W_in + (size_t)r * 784 + c);
        o.x = f2b(v.x); o.y = f2b(v.y); o.z = f2b(v.z); o.w = f2b(v.w);
    }
    *(ushort4*)(W_inb + (size_t)r * KI + c) = o;
}

// ============================================================================
extern "C" void kernel_launch(void* const* d_in, const int* in_sizes, int n_in,
                              void* d_out, int out_size, void* d_ws, size_t ws_size,
                              hipStream_t stream)
{
    const float* z     = (const float*)d_in[0];
    const float* ne    = (const float*)d_in[1];
    const float* note  = (const float*)d_in[3];
    const float* velc  = (const float*)d_in[4];
    const float* gc    = (const float*)d_in[5];
    const float* W_in  = (const float*)d_in[6];
    const float* b_in  = (const float*)d_in[7];
    const float* W_ih1 = (const float*)d_in[8];
    const float* W_hh1 = (const float*)d_in[9];
    const float* b_ih1 = (const float*)d_in[10];
    const float* b_hh1 = (const float*)d_in[11];
    const float* W_ih2 = (const float*)d_in[12];
    const float* W_hh2 = (const float*)d_in[13];
    const float* b_ih2 = (const float*)d_in[14];
    const float* b_hh2 = (const float*)d_in[15];
    const float* W_out = (const float*)d_in[16];
    const float* b_out = (const float*)d_in[17];
    float* out = (float*)d_out;

    // workspace layout (~44.3 MB)
    float*  h1   = (float*)d_ws;                     // [512*1024]
    float*  h2   = h1 + BB * HD;                     // [512*1024]
    float*  Cbuf = h2 + BB * HD;                     // [512*9216]
    float*  Wt1  = Cbuf + (size_t)BB * NC;           // [22*3072]
    ushort* h1b  = (ushort*)(Wt1 + 22 * N3);         // [512*1024]
    ushort* h2b  = h1b + BB * HD;                    // [512*1024]
    ushort* Wcat = h2b + BB * HD;                    // [9216*1024]
    // init-only buffers aliased into Cbuf (consumed before Cbuf is written)
    ushort* Acat  = (ushort*)Cbuf;                   // [512*832]
    ushort* W_inb = Acat + (size_t)BB * KI;          // [1024*832]

    prep_w   <<<dim3(NC), 256, 0, stream>>>(W_ih2, W_hh1, W_hh2, Wcat);
    prep_wt1 <<<dim3(12), 256, 0, stream>>>(W_ih1, Wt1);
    prep_acat<<<dim3(BB), 256, 0, stream>>>(z, ne, gc, Acat);
    prep_win <<<dim3(HD), 256, 0, stream>>>(W_in, W_inb);

    PArgs pa;
    pa.h1 = h1; pa.h2 = h2; pa.Cbuf = Cbuf; pa.Wt1 = Wt1;
    pa.h1b = h1b; pa.h2b = h2b; pa.Wcat = Wcat;
    pa.Acat = Acat; pa.W_inb = W_inb;
    pa.note = note; pa.velc = velc;
    pa.b_in = b_in; pa.b_ih1 = b_ih1; pa.b_hh1 = b_hh1;
    pa.b_ih2 = b_ih2; pa.b_hh2 = b_hh2;
    pa.W_out = W_out; pa.b_out = b_out;
    pa.out = out;

    k_init<<<dim3(128), 256, 0, stream>>>(pa);
    k_gemm<<<dim3(8, 48), 256, 0, stream>>>(pa, 48);   // prologue gh1(0)
    k_pwf <<<dim3(BB), 256, 0, stream>>>(pa);
    for (int s = 0; s < SS; ++s) {
        k_gemm<<<dim3(8, 144), 256, 0, stream>>>(pa, 0);  // gi2|gh1'|gh2
        k_pw  <<<dim3(BB / 2), 256, 0, stream>>>(pa, s);
    }
}

// Round 10
// 2093.978 us; speedup vs baseline: 8.4692x; 1.3821x over previous
//
#include <hip/hip_runtime.h>
#include <hip/hip_bf16.h>

#define HD 1024
#define BB 512
#define SS 64
#define N3 3072
#define NC 9216      // 3 * N3  (gi2 | gh1 | gh2)
#define ND 9
#define VC 4
#define KI 832       // padded K for init GEMM (784 -> 13*64)

typedef __attribute__((ext_vector_type(8))) short bf16x8;
typedef __attribute__((ext_vector_type(4))) float f32x4;

__device__ __forceinline__ ushort f2b(float f) {
    unsigned u = __builtin_bit_cast(unsigned, f);
    u += 0x7fffu + ((u >> 16) & 1u);          // round-to-nearest-even
    return (ushort)(u >> 16);
}

__device__ __forceinline__ float sigf(float x) {
    return 1.f / (1.f + __expf(-x));
}

__device__ __forceinline__ void gld_lds16(const void* g, void* l) {
    __builtin_amdgcn_global_load_lds(
        (const __attribute__((address_space(1))) unsigned int*)g,
        (__attribute__((address_space(3))) unsigned int*)l, 16, 0, 0);
}

// ============================================================================
// prep kernels
// ============================================================================
__global__ __launch_bounds__(256) void prep_w(
    const float* __restrict__ Wih2, const float* __restrict__ Whh1,
    const float* __restrict__ Whh2, ushort* __restrict__ Wcat)
{
    const int row = blockIdx.x;
    const float* src = row < 3072 ? Wih2 + (size_t)row * HD
                     : row < 6144 ? Whh1 + (size_t)(row - 3072) * HD
                                  : Whh2 + (size_t)(row - 6144) * HD;
    const int c = threadIdx.x * 4;
    float4 v = *(const float4*)(src + c);
    ushort4 o;
    o.x = f2b(v.x); o.y = f2b(v.y); o.z = f2b(v.z); o.w = f2b(v.w);
    *(ushort4*)(Wcat + (size_t)row * HD + c) = o;
}

__global__ __launch_bounds__(256) void prep_wt1(
    const float* __restrict__ Wih1, float* __restrict__ Wt1)
{
    const int g = blockIdx.x * 256 + threadIdx.x;
    #pragma unroll
    for (int c = 0; c < 22; ++c)
        Wt1[c * N3 + g] = Wih1[(size_t)g * 22 + c];
}

__global__ __launch_bounds__(256) void prep_acat(
    const float* __restrict__ z, const float* __restrict__ ne,
    const float* __restrict__ gc, ushort* __restrict__ Acat)
{
    const int b = blockIdx.x;
    const int t = threadIdx.x;
    if (t >= 208) return;
    const int c = t * 4;
    float4 v = make_float4(0.f, 0.f, 0.f, 0.f);
    if (c < 256)      v = *(const float4*)(z  + (size_t)b * 256 + c);
    else if (c < 768) v = *(const float4*)(ne + (size_t)b * 512 + (c - 256));
    else if (c < 784) v = *(const float4*)(gc + (size_t)b * 16  + (c - 768));
    ushort4 o;
    o.x = f2b(v.x); o.y = f2b(v.y); o.z = f2b(v.z); o.w = f2b(v.w);
    *(ushort4*)(Acat + (size_t)b * KI + c) = o;
}

__global__ __launch_bounds__(256) void prep_win(
    const float* __restrict__ W_in, ushort* __restrict__ W_inb)
{
    const int r = blockIdx.x;
    const int t = threadIdx.x;
    if (t >= 208) return;
    const int c = t * 4;
    ushort4 o = {0, 0, 0, 0};
    if (c < 784) {
        float4 v = *(const float4*)(W_in + (size_t)r * 784 + c);
        o.x = f2b(v.x); o.y = f2b(v.y); o.z = f2b(v.z); o.w = f2b(v.w);
    }
    *(ushort4*)(W_inb + (size_t)r * KI + c) = o;
}

// ============================================================================
// k_init: h1 = tanh(Acat @ W_inb^T + b_in). 64x64 tiles, dbuf core (runs once;
// verified in round 9). Writes h1 f32 + h1b bf16.
// ============================================================================
__global__ __launch_bounds__(256) void k_init(
    const ushort* __restrict__ Acat, const ushort* __restrict__ W_inb,
    const float* __restrict__ b_in, float* __restrict__ h1, ushort* __restrict__ h1b)
{
    __shared__ __align__(16) ushort As[2 * 4096];
    __shared__ __align__(16) ushort Bs[2 * 4096];
    const int t = blockIdx.x;
    const int nt = t >> 3, mt = t & 7;

    const int tid = threadIdx.x;
    const int w = tid >> 6, l = tid & 63;
    const int lr = l >> 3;
    const int sw = ((l & 7) ^ lr) << 3;

    const ushort* Ag0 = Acat + ((size_t)(mt << 6)) * KI + (size_t)(16 * w + lr) * KI + sw;
    const ushort* Ag1 = Ag0 + 8 * KI;
    const ushort* Bg0 = W_inb + ((size_t)(nt << 6)) * KI + (size_t)(16 * w + lr) * KI + sw;
    const ushort* Bg1 = Bg0 + 8 * KI;
    const int o0 = (16 * w) * 64, o1 = (16 * w + 8) * 64;

    gld_lds16(Ag0, As + o0); gld_lds16(Ag1, As + o1);
    gld_lds16(Bg0, Bs + o0); gld_lds16(Bg1, Bs + o1);

    const int wm = (w >> 1) << 5, wn = (w & 1) << 5;
    const int fr = l & 15, fc = l >> 4;
    const int ra0 = wm + fr, ra1 = wm + 16 + fr;
    const int rb0 = wn + fr, rb1 = wn + 16 + fr;

    f32x4 acc[2][2] = {};
    for (int kt = 0; kt < 13; ++kt) {
        const int cb = (kt & 1) << 12;
        __syncthreads();
        if (kt + 1 < 13) {
            const int nb = ((kt + 1) & 1) << 12;
            const int ko = (kt + 1) << 6;
            gld_lds16(Ag0 + ko, As + nb + o0);
            gld_lds16(Ag1 + ko, As + nb + o1);
            gld_lds16(Bg0 + ko, Bs + nb + o0);
            gld_lds16(Bg1 + ko, Bs + nb + o1);
        }
        #pragma unroll
        for (int kk = 0; kk < 2; ++kk) {
            const int c = (kk << 2) + fc;
            bf16x8 a0 = *(const bf16x8*)(As + cb + ra0 * 64 + ((c ^ (ra0 & 7)) << 3));
            bf16x8 a1 = *(const bf16x8*)(As + cb + ra1 * 64 + ((c ^ (ra1 & 7)) << 3));
            bf16x8 b0 = *(const bf16x8*)(Bs + cb + rb0 * 64 + ((c ^ (rb0 & 7)) << 3));
            bf16x8 b1 = *(const bf16x8*)(Bs + cb + rb1 * 64 + ((c ^ (rb1 & 7)) << 3));
            acc[0][0] = __builtin_amdgcn_mfma_f32_16x16x32_bf16(a0, b0, acc[0][0], 0, 0, 0);
            acc[0][1] = __builtin_amdgcn_mfma_f32_16x16x32_bf16(a0, b1, acc[0][1], 0, 0, 0);
            acc[1][0] = __builtin_amdgcn_mfma_f32_16x16x32_bf16(a1, b0, acc[1][0], 0, 0, 0);
            acc[1][1] = __builtin_amdgcn_mfma_f32_16x16x32_bf16(a1, b1, acc[1][1], 0, 0, 0);
        }
    }

    const int row0 = (mt << 6) + wm;
    const int col0 = (nt << 6) + wn + fr;
    const float b0v = b_in[col0], b1v = b_in[col0 + 16];
    #pragma unroll
    for (int i = 0; i < 2; ++i) {
        #pragma unroll
        for (int r = 0; r < 4; ++r) {
            const int row = row0 + i * 16 + fc * 4 + r;
            const float v0 = tanhf(acc[i][0][r] + b0v);
            const float v1 = tanhf(acc[i][1][r] + b1v);
            h1[(size_t)row * HD + col0]       = v0;
            h1b[(size_t)row * HD + col0]      = f2b(v0);
            h1[(size_t)row * HD + col0 + 16]  = v1;
            h1b[(size_t)row * HD + col0 + 16] = f2b(v1);
        }
    }
}

// ============================================================================
// gemm3: C[512, 9216] = [h1b@Wih2^T | h1b@Whh1^T | h2b@Whh2^T]
// ROUND-2 EXACT kernel: 64x64 tile, single-buffered 16KB LDS, 4 waves,
// mfma_f32_16x16x32_bf16, global_load_lds w16 + XOR-swizzled source,
// XCD-bijective block swizzle. Best measured structure (2150 us total).
// ============================================================================
__global__ __launch_bounds__(256) void gemm3(
    const ushort* __restrict__ h1b, const ushort* __restrict__ h2b,
    const ushort* __restrict__ Wcat, float* __restrict__ Cbuf, int ntb)
{
    __shared__ __align__(16) ushort As[4096];   // [64][64] linear
    __shared__ __align__(16) ushort Ws[4096];

    const int flat = blockIdx.x + (blockIdx.y << 3);
    const int id   = (flat & 7) * gridDim.y + (flat >> 3);
    const int bm   = (id & 7) << 6;
    const int nt   = (id >> 3) + ntb;          // global n-tile 0..143

    const ushort* Amat = (nt < 96) ? h1b : h2b;
    const ushort* W    = Wcat + (size_t)(nt << 6) * HD;

    const int tid = threadIdx.x;
    const int w   = tid >> 6;
    const int l   = tid & 63;

    const int srow = l >> 3;
    const int sch  = ((l & 7) ^ srow) << 3;
    const ushort* Ag0 = Amat + (size_t)(bm + 16 * w + srow) * HD + sch;
    const ushort* Ag1 = Ag0 + 8 * HD;
    const ushort* Wg0 = W + (size_t)(16 * w + srow) * HD + sch;
    const ushort* Wg1 = Wg0 + 8 * HD;
    ushort* Al0 = As + (16 * w) * 64;
    ushort* Al1 = As + (16 * w + 8) * 64;
    ushort* Wl0 = Ws + (16 * w) * 64;
    ushort* Wl1 = Ws + (16 * w + 8) * 64;

    const int wm = (w >> 1) << 5;
    const int wn = (w & 1) << 5;
    const int fr = l & 15;
    const int fc = l >> 4;

    const int ra0 = wm + fr,  ra1 = wm + 16 + fr;
    const int rb0 = wn + fr,  rb1 = wn + 16 + fr;

    f32x4 acc00 = {0.f,0.f,0.f,0.f}, acc01 = {0.f,0.f,0.f,0.f};
    f32x4 acc10 = {0.f,0.f,0.f,0.f}, acc11 = {0.f,0.f,0.f,0.f};

    for (int kt = 0; kt < 16; ++kt) {
        const int ko = kt << 6;
        __syncthreads();
        gld_lds16(Ag0 + ko, Al0);
        gld_lds16(Ag1 + ko, Al1);
        gld_lds16(Wg0 + ko, Wl0);
        gld_lds16(Wg1 + ko, Wl1);
        __syncthreads();
        #pragma unroll
        for (int kk = 0; kk < 2; ++kk) {
            const int c = (kk << 2) + fc;
            bf16x8 a0 = *(const bf16x8*)(As + ra0 * 64 + ((c ^ (ra0 & 7)) << 3));
            bf16x8 a1 = *(const bf16x8*)(As + ra1 * 64 + ((c ^ (ra1 & 7)) << 3));
            bf16x8 b0 = *(const bf16x8*)(Ws + rb0 * 64 + ((c ^ (rb0 & 7)) << 3));
            bf16x8 b1 = *(const bf16x8*)(Ws + rb1 * 64 + ((c ^ (rb1 & 7)) << 3));
            acc00 = __builtin_amdgcn_mfma_f32_16x16x32_bf16(a0, b0, acc00, 0, 0, 0);
            acc01 = __builtin_amdgcn_mfma_f32_16x16x32_bf16(a0, b1, acc01, 0, 0, 0);
            acc10 = __builtin_amdgcn_mfma_f32_16x16x32_bf16(a1, b0, acc10, 0, 0, 0);
            acc11 = __builtin_amdgcn_mfma_f32_16x16x32_bf16(a1, b1, acc11, 0, 0, 0);
        }
    }

    const int bn = nt << 6;
    float* Cw = Cbuf + (size_t)(bm + wm) * NC + bn + wn;
    #pragma unroll
    for (int r = 0; r < 4; ++r) {
        const size_t ro0 = (size_t)(fc * 4 + r) * NC;
        const size_t ro1 = (size_t)(16 + fc * 4 + r) * NC;
        Cw[ro0 + fr]      = acc00[r];
        Cw[ro0 + 16 + fr] = acc01[r];
        Cw[ro1 + fr]      = acc10[r];
        Cw[ro1 + 16 + fr] = acc11[r];
    }
}

// ============================================================================
// gru1_first: step-0 GRU1 (out_prev = 0); writes h1,h1b and copies to h2,h2b.
// Round-3 exact. grid (512) x 1024 threads.
// ============================================================================
__global__ __launch_bounds__(1024) void gru1_first(
    const float* __restrict__ Cbuf, float* __restrict__ h1, ushort* __restrict__ h1b,
    float* __restrict__ h2, ushort* __restrict__ h2b,
    const float* __restrict__ note, const float* __restrict__ velc,
    const float* __restrict__ Wt1, const float* __restrict__ b_ih1,
    const float* __restrict__ b_hh1)
{
    __shared__ float inp[22];
    const int b = blockIdx.x;
    const int j = threadIdx.x;

    if (j < 22) {
        float v = 0.f;
        if (j >= 9 && j < 18) v = note[(size_t)b * (SS * ND) + (j - 9)];
        else if (j >= 18)     v = velc[(size_t)b * (SS * VC) + (j - 18)];
        inp[j] = v;
    }
    __syncthreads();

    float ir = b_ih1[j], iz = b_ih1[HD + j], inn = b_ih1[2 * HD + j];
    #pragma unroll
    for (int c = 0; c < 22; ++c) {
        const float x = inp[c];
        const float* wr = Wt1 + c * N3;
        ir  = fmaf(x, wr[j],          ir);
        iz  = fmaf(x, wr[HD + j],     iz);
        inn = fmaf(x, wr[2 * HD + j], inn);
    }

    const float* g = Cbuf + (size_t)b * NC + N3;     // gh1 section
    const float hr = g[j]          + b_hh1[j];
    const float hz = g[HD + j]     + b_hh1[HD + j];
    const float hn = g[2 * HD + j] + b_hh1[2 * HD + j];

    const float rg = sigf(ir + hr);
    const float zg = sigf(iz + hz);
    const float n  = tanhf(inn + rg * hn);
    const float hnew = (1.f - zg) * n + zg * h1[(size_t)b * HD + j];
    const ushort hb = f2b(hnew);
    h1[(size_t)b * HD + j]  = hnew;
    h1b[(size_t)b * HD + j] = hb;
    h2[(size_t)b * HD + j]  = hnew;
    h2b[(size_t)b * HD + j] = hb;
}

// ============================================================================
// pw_fused(step): GRU2 -> h2,h2b ; out[step] ; GRU1(step+1) -> h1,h1b.
// Round-3 exact. grid (512) x 1024 threads.
// ============================================================================
__global__ __launch_bounds__(1024) void pw_fused(
    const float* __restrict__ Cbuf, float* __restrict__ h1, ushort* __restrict__ h1b,
    float* __restrict__ h2, ushort* __restrict__ h2b,
    const float* __restrict__ note, const float* __restrict__ velc,
    const float* __restrict__ Wt1,
    const float* __restrict__ b_ih1, const float* __restrict__ b_hh1,
    const float* __restrict__ b_ih2, const float* __restrict__ b_hh2,
    const float* __restrict__ W_out, const float* __restrict__ b_out,
    float* __restrict__ dout, int step)
{
    __shared__ float hs[HD];
    __shared__ float inp[22];
    const int b = blockIdx.x;
    const int j = threadIdx.x;

    // stage next-step note/velc while GRU2 runs
    if (step + 1 < SS && j >= 9 && j < 22) {
        inp[j] = (j < 18) ? note[(size_t)b * (SS * ND) + (step + 1) * ND + (j - 9)]
                          : velc[(size_t)b * (SS * VC) + (step + 1) * VC + (j - 18)];
    }

    const float* gi = Cbuf + (size_t)b * NC;          // gi2
    const float* gh = gi + 2 * N3;                    // gh2

    const float ir  = gi[j]          + b_ih2[j];
    const float hr  = gh[j]          + b_hh2[j];
    const float iz  = gi[HD + j]     + b_ih2[HD + j];
    const float hz  = gh[HD + j]     + b_hh2[HD + j];
    const float inn = gi[2 * HD + j] + b_ih2[2 * HD + j];
    const float hn  = gh[2 * HD + j] + b_hh2[2 * HD + j];

    const float rg = sigf(ir + hr);
    const float zg = sigf(iz + hz);
    const float n  = tanhf(inn + rg * hn);
    const float hnew = (1.f - zg) * n + zg * h2[(size_t)b * HD + j];
    h2[(size_t)b * HD + j]  = hnew;
    h2b[(size_t)b * HD + j] = f2b(hnew);
    hs[j] = hnew;
    __syncthreads();

    // out[b, step, :]
    const int w = j >> 6;
    const int t = j & 63;
    if (w < ND) {
        float a = 0.f;
        const float* wr = W_out + (size_t)w * HD;
        #pragma unroll
        for (int k = 0; k < HD / 64; ++k)
            a = fmaf(hs[t + k * 64], wr[t + k * 64], a);
        #pragma unroll
        for (int off = 32; off > 0; off >>= 1) a += __shfl_down(a, off);
        if (t == 0) {
            const float o = sigf(a + b_out[w]);
            dout[(size_t)b * (SS * ND) + step * ND + w] = o;
            inp[w] = o;
        }
    }
    __syncthreads();

    // GRU1 for step+1
    if (step + 1 < SS) {
        float xir = b_ih1[j], xiz = b_ih1[HD + j], xinn = b_ih1[2 * HD + j];
        #pragma unroll
        for (int c = 0; c < 22; ++c) {
            const float x = inp[c];
            const float* wr = Wt1 + c * N3;
            xir  = fmaf(x, wr[j],          xir);
            xiz  = fmaf(x, wr[HD + j],     xiz);
            xinn = fmaf(x, wr[2 * HD + j], xinn);
        }
        const float* g1 = Cbuf + (size_t)b * NC + N3;  // gh1 (for step+1)
        const float hr1 = g1[j]          + b_hh1[j];
        const float hz1 = g1[HD + j]     + b_hh1[HD + j];
        const float hn1 = g1[2 * HD + j] + b_hh1[2 * HD + j];

        const float rg1 = sigf(xir + hr1);
        const float zg1 = sigf(xiz + hz1);
        const float n1  = tanhf(xinn + rg1 * hn1);
        const float h1new = (1.f - zg1) * n1 + zg1 * h1[(size_t)b * HD + j];
        h1[(size_t)b * HD + j]  = h1new;
        h1b[(size_t)b * HD + j] = f2b(h1new);
    }
}

// ============================================================================
extern "C" void kernel_launch(void* const* d_in, const int* in_sizes, int n_in,
                              void* d_out, int out_size, void* d_ws, size_t ws_size,
                              hipStream_t stream)
{
    const float* z     = (const float*)d_in[0];
    const float* ne    = (const float*)d_in[1];
    const float* note  = (const float*)d_in[3];
    const float* velc  = (const float*)d_in[4];
    const float* gc    = (const float*)d_in[5];
    const float* W_in  = (const float*)d_in[6];
    const float* b_in  = (const float*)d_in[7];
    const float* W_ih1 = (const float*)d_in[8];
    const float* W_hh1 = (const float*)d_in[9];
    const float* b_ih1 = (const float*)d_in[10];
    const float* b_hh1 = (const float*)d_in[11];
    const float* W_ih2 = (const float*)d_in[12];
    const float* W_hh2 = (const float*)d_in[13];
    const float* b_ih2 = (const float*)d_in[14];
    const float* b_hh2 = (const float*)d_in[15];
    const float* W_out = (const float*)d_in[16];
    const float* b_out = (const float*)d_in[17];
    float* out = (float*)d_out;

    // workspace layout (~44.3 MB)
    float*  h1   = (float*)d_ws;                     // [512*1024]
    float*  h2   = h1 + BB * HD;                     // [512*1024]
    float*  Cbuf = h2 + BB * HD;                     // [512*9216]
    float*  Wt1  = Cbuf + (size_t)BB * NC;           // [22*3072]
    ushort* h1b  = (ushort*)(Wt1 + 22 * N3);         // [512*1024]
    ushort* h2b  = h1b + BB * HD;                    // [512*1024]
    ushort* Wcat = h2b + BB * HD;                    // [9216*1024]
    // init-only buffers aliased into Cbuf (consumed before Cbuf is written)
    ushort* Acat  = (ushort*)Cbuf;                   // [512*832]
    ushort* W_inb = Acat + (size_t)BB * KI;          // [1024*832]

    prep_w   <<<dim3(NC), 256, 0, stream>>>(W_ih2, W_hh1, W_hh2, Wcat);
    prep_wt1 <<<dim3(12), 256, 0, stream>>>(W_ih1, Wt1);
    prep_acat<<<dim3(BB), 256, 0, stream>>>(z, ne, gc, Acat);
    prep_win <<<dim3(HD), 256, 0, stream>>>(W_in, W_inb);

    k_init<<<dim3(128), 256, 0, stream>>>(Acat, W_inb, b_in, h1, h1b);

    // prologue: gh1(0)  (n-tiles 48..95)
    gemm3<<<dim3(8, 48), 256, 0, stream>>>(h1b, h2b, Wcat, Cbuf, 48);
    gru1_first<<<dim3(BB), 1024, 0, stream>>>(Cbuf, h1, h1b, h2, h2b,
                                              note, velc, Wt1, b_ih1, b_hh1);

    for (int s = 0; s < SS; ++s) {
        // gi2(s) | gh1(s+1) | gh2(s)
        gemm3<<<dim3(8, 144), 256, 0, stream>>>(h1b, h2b, Wcat, Cbuf, 0);
        pw_fused<<<dim3(BB), 1024, 0, stream>>>(Cbuf, h1, h1b, h2, h2b,
                                                note, velc, Wt1,
                                                b_ih1, b_hh1, b_ih2, b_hh2,
                                                W_out, b_out, out, s);
    }
}